// Round 12
// baseline (389.676 us; speedup 1.0000x reference)
//
#include <hip/hip_runtime.h>

// 2-layer LSTM, B=4096, T=168, D=16, H1=64, H2=32, fp32 in/out.
// R12 = R11 + barrier-latency decoupling:
//  - x prefetched TWO intervals ahead (3-stage xc/xn/xt2 rotation, load issued
//    first in the interval): the compiler's pre-s_barrier `s_waitcnt vmcnt(0)`
//    drain no longer waits on HBM-latency x loads (~900 cyc misses with only
//    1-interval slack in R11).
//  - W_ih2-lo fragments moved from LDS into L2a-branch registers (branch
//    live-set is below the kernel's 128-VGPR watermark -> free); kills 8
//    ds_read_b128/interval + 16 KB LDS.
// Roles (512 thr/block, grid 256, 1 block/CU, 2 waves/SIMD):
//   w0-3 : h1(t)   = LSTM1(h1(t-1), x(t))            [32 MFMA, lo*lo dropped]
//   w6,7 : pA(t-1) = full W_ih2 . h1(t-1)            [24 MFMA]
//   w4,5 : h2(t-2) = act(pA(t-2) + W_hh2 . h2(t-3))  [12 MFMA, self-recurrent]
// mfma_f32_16x16x32_bf16 hi/lo split, lo*lo dropped; split_fast trunc splits.

typedef __bf16 bf16x8 __attribute__((ext_vector_type(8)));
typedef float  f32x4  __attribute__((ext_vector_type(4)));

constexpr int T_SEQ = 168;
constexpr int NB    = 16;

__device__ __forceinline__ float fsig(float v)  { return __builtin_amdgcn_rcpf(1.f + __expf(-v)); }
__device__ __forceinline__ float ftanhf(float v){ return 2.f * __builtin_amdgcn_rcpf(1.f + __expf(-2.f * v)) - 1.f; }

// init-time rne split
__device__ __forceinline__ void split_bf16(float x, __bf16& hi, __bf16& lo) {
  hi = (__bf16)x;
  lo = (__bf16)(x - (float)hi);
}

// hot-loop split: pure integer ops (validated R11: absmax 1.2e-4)
__device__ __forceinline__ void split_fast(float x, __bf16& hi, __bf16& lo) {
  const unsigned u  = __float_as_uint(x);
  const unsigned hb = u & 0xFFFF0000u;
  const float    lf = x - __uint_as_float(hb);
  hi = __builtin_bit_cast(__bf16, (unsigned short)(hb >> 16));
  lo = __builtin_bit_cast(__bf16, (unsigned short)(__float_as_uint(lf) >> 16));
}

__device__ __forceinline__ void load_frag8(const float* __restrict__ Wrow, int k0,
                                           bf16x8& hi, bf16x8& lo) {
#pragma unroll
  for (int j = 0; j < 8; ++j) {
    float v = Wrow[k0 + j];
    __bf16 h = (__bf16)v;
    hi[j] = h;
    lo[j] = (__bf16)(v - (float)h);
  }
}

#define MFMA(a, b, c) __builtin_amdgcn_mfma_f32_16x16x32_bf16((a), (b), (c), 0, 0, 0)

__global__ __launch_bounds__(512) __attribute__((amdgpu_waves_per_eu(2, 2)))
void lstm_mfma_kernel(const float* __restrict__ x,
    const float* __restrict__ Wih1, const float* __restrict__ Whh1,
    const float* __restrict__ bih1, const float* __restrict__ bhh1,
    const float* __restrict__ Wih2, const float* __restrict__ Whh2,
    const float* __restrict__ bih2, const float* __restrict__ bhh2,
    const float* __restrict__ Wfc,  const float* __restrict__ bfc,
    float* __restrict__ out)
{
  __shared__ __align__(16) __bf16 sA1[2][4 * 64 * 8];      // h1 hi(kb0,1)/lo(kb2,3) (8 KB)
  __shared__ __align__(16) __bf16 sA2[2][2 * 64 * 8];      // h2 hi(kb0)/lo(kb1) (4 KB)
  __shared__ __align__(16) float  sP[2][2 * 4 * 64 * 4];   // pA partials, ping-pong (16 KB)
  __shared__ __align__(16) float  sH2f[16 * 32];           // final h2 [batch][unit]

  const int tid  = threadIdx.x;
  const int w    = tid >> 6;        // wave 0..7
  const int lane = tid & 63;
  const int q    = lane >> 4;
  const int col  = lane & 15;
  const int b0   = blockIdx.x * NB;

  const bool isL1  = (w < 4);
  const bool isL2b = (w == 4) || (w == 5);
  const bool isL2a = (w >= 6);
  const int  wl2b  = w - 4;
  const int  wl2a  = w - 6;

  if (isL1) __builtin_amdgcn_s_setprio(1);

  // ---------------- L1 weights into registers ----------------
  bf16x8 bhh[4][4];   // W_hh1 hi(kb0,1)/lo(kb2,3)
  bf16x8 bih[4];      // W_ih1 packed [Wh;Wl]
  f32x4  b1sd[4];
  if (isL1) {
#pragma unroll
    for (int g = 0; g < 4; ++g) {
      const int r = g * 64 + w * 16 + col;
      const float* Wr = Whh1 + r * 64;
      bf16x8 h0, l0, h1f, l1f;
      load_frag8(Wr, 0 * 32 + q * 8, h0, l0);
      load_frag8(Wr, 1 * 32 + q * 8, h1f, l1f);
      bhh[g][0] = h0; bhh[g][1] = h1f; bhh[g][2] = l0; bhh[g][3] = l1f;
      bf16x8 xh, xl;
      load_frag8(Wih1 + r * 16, (q & 1) * 8, xh, xl);
      bih[g] = (q < 2) ? xh : xl;
      const float bv = bih1[r] + bhh1[r];
      b1sd[g][0] = bv; b1sd[g][1] = bv; b1sd[g][2] = bv; b1sd[g][3] = bv;
    }
  }
  // ---------------- L2b weights: W_hh2 hi/lo ----------------
  bf16x8 wh2h[4], wh2l[4];
  f32x4  b2sd[4];
  if (isL2b) {
#pragma unroll
    for (int g = 0; g < 4; ++g) {
      const int r = g * 32 + wl2b * 16 + col;
      bf16x8 hh, ll;
      load_frag8(Whh2 + r * 32, q * 8, hh, ll);
      wh2h[g] = hh; wh2l[g] = ll;
      const float bv = bih2[r] + bhh2[r];
      b2sd[g][0] = bv; b2sd[g][1] = bv; b2sd[g][2] = bv; b2sd[g][3] = bv;
    }
  }
  // ---------------- L2a weights: W_ih2 HI + LO (all in registers) ----------------
  bf16x8 w2ih[4][2], w2il[4][2];
  if (isL2a) {
#pragma unroll
    for (int g = 0; g < 4; ++g) {
      const int r = g * 32 + wl2a * 16 + col;
#pragma unroll
      for (int kb = 0; kb < 2; ++kb) {
        bf16x8 hh, ll;
        load_frag8(Wih2 + r * 64, kb * 32 + q * 8, hh, ll);
        w2ih[g][kb] = hh;
        w2il[g][kb] = ll;
      }
    }
  }

  // ---------------- zero state buffers ----------------
  {
    bf16x8 z;
#pragma unroll
    for (int j = 0; j < 8; ++j) z[j] = (__bf16)0.f;
    for (int i = tid; i < 2 * 4 * 64; i += 512) *(bf16x8*)&sA1[0][i * 8] = z;
    for (int i = tid; i < 2 * 2 * 64; i += 512) *(bf16x8*)&sA2[0][i * 8] = z;
  }
  __syncthreads();

  // x prefetch: 3-stage rotation xc (current), xn (t+1), xt2 (t+2 in flight)
  const float* xbase = x + ((size_t)(b0 + col) * T_SEQ) * 16 + (q & 1) * 8;
  float4 xcA, xcB, xnA, xnB;
  if (isL1) {
    xcA = *(const float4*)(xbase + 0);    // x(0)
    xcB = *(const float4*)(xbase + 4);
    xnA = *(const float4*)(xbase + 16);   // x(1)
    xnB = *(const float4*)(xbase + 20);
  }

  float c1s[4] = {0.f, 0.f, 0.f, 0.f};
  float c2s[4] = {0.f, 0.f, 0.f, 0.f};
  const int uu   = w * 16 + col;
  const int uu2b = wl2b * 16 + col;

  const int kbh  = uu >> 5;
  const int lnb  = ((uu & 31) >> 3) * 16;
  const int jj   = uu & 7;
  const int lnb2 = ((uu2b & 31) >> 3) * 16;
  const int jj2  = uu2b & 7;

  const f32x4 z4 = {0.f, 0.f, 0.f, 0.f};

// One pipeline interval. Pc and DO_* are compile-time literals.
// DO_XPRE is true iff TT+2 <= 167 (load for x(TT+2)).
#define STEP(Pc, DO_L1, DO_XPRE, DO_L2A, DO_L2B, DO_H2F, TT) do {              \
    if ((DO_L1) && isL1) {                                                     \
      float4 xt2A, xt2B;                                                       \
      if (DO_XPRE) {   /* issued FIRST: ~2 intervals of slack before drain */  \
        const float* xr = xbase + (size_t)((TT) + 2) * 16;                     \
        xt2A = *(const float4*)(xr + 0);                                       \
        xt2B = *(const float4*)(xr + 4);                                       \
      }                                                                        \
      bf16x8 a1[4];                                                            \
      _Pragma("unroll")                                                        \
      for (int kb = 0; kb < 4; ++kb)                                           \
        a1[kb] = *(const bf16x8*)&sA1[(Pc)][(kb * 64 + lane) * 8];             \
      const float xc[8] = {xcA.x, xcA.y, xcA.z, xcA.w, xcB.x, xcB.y, xcB.z, xcB.w}; \
      bf16x8 xh8, xl8;                                                         \
      _Pragma("unroll")                                                        \
      for (int j = 0; j < 8; ++j) {                                            \
        __bf16 h_, l_; split_fast(xc[j], h_, l_);                              \
        xh8[j] = h_; xl8[j] = l_;                                              \
      }                                                                        \
      const bf16x8 ax0 = (q < 2) ? xh8 : xl8;                                  \
      const bf16x8 ax1 = (q < 2) ? xl8 : xh8;                                  \
      f32x4 ca[4], cb[4];                                                      \
      _Pragma("unroll")                                                        \
      for (int g = 0; g < 4; ++g) {                                            \
        ca[g] = MFMA(ax0,   bih[g],    b1sd[g]);                               \
        ca[g] = MFMA(ax1,   bih[g],    ca[g]);                                 \
        ca[g] = MFMA(a1[0], bhh[g][0], ca[g]);                                 \
        ca[g] = MFMA(a1[1], bhh[g][1], ca[g]);                                 \
        cb[g] = MFMA(a1[2], bhh[g][0], z4);                                    \
        cb[g] = MFMA(a1[3], bhh[g][1], cb[g]);                                 \
        cb[g] = MFMA(a1[0], bhh[g][2], cb[g]);                                 \
        cb[g] = MFMA(a1[1], bhh[g][3], cb[g]);                                 \
      }                                                                        \
      _Pragma("unroll")                                                        \
      for (int r = 0; r < 4; ++r) {                                            \
        const float iv = fsig(ca[0][r] + cb[0][r]);                            \
        const float fv = fsig(ca[1][r] + cb[1][r]);                            \
        const float gv = ftanhf(ca[2][r] + cb[2][r]);                          \
        const float ov = fsig(ca[3][r] + cb[3][r]);                            \
        const float cc = fmaf(fv, c1s[r], iv * gv);                            \
        c1s[r] = cc;                                                           \
        __bf16 hh_, hl_;                                                       \
        split_fast(ov * ftanhf(cc), hh_, hl_);                                 \
        const int m = q * 4 + r;                                               \
        sA1[1 - (Pc)][((kbh * 64) + lnb + m) * 8 + jj]       = hh_;            \
        sA1[1 - (Pc)][(((2 + kbh) * 64) + lnb + m) * 8 + jj] = hl_;            \
      }                                                                        \
      xcA = xnA; xcB = xnB;                                                    \
      if (DO_XPRE) { xnA = xt2A; xnB = xt2B; }                                 \
    }                                                                          \
    if ((DO_L2A) && isL2a) {                                                   \
      bf16x8 a2[4];                                                            \
      _Pragma("unroll")                                                        \
      for (int kb = 0; kb < 4; ++kb)                                           \
        a2[kb] = *(const bf16x8*)&sA1[(Pc)][(kb * 64 + lane) * 8];             \
      _Pragma("unroll")                                                        \
      for (int g = 0; g < 4; ++g) {                                            \
        f32x4 pa;                                                              \
        pa = MFMA(a2[0], w2ih[g][0], z4);    /* hi x hi */                     \
        pa = MFMA(a2[1], w2ih[g][1], pa);                                      \
        pa = MFMA(a2[0], w2il[g][0], pa);    /* hi x lo */                     \
        pa = MFMA(a2[1], w2il[g][1], pa);                                      \
        pa = MFMA(a2[2], w2ih[g][0], pa);    /* lo x hi */                     \
        pa = MFMA(a2[3], w2ih[g][1], pa);                                      \
        *(f32x4*)&sP[(Pc)][((wl2a * 4 + g) * 64 + lane) * 4] = pa;             \
      }                                                                        \
    }                                                                          \
    if ((DO_L2B) && isL2b) {                                                   \
      const bf16x8 ah0 = *(const bf16x8*)&sA2[1 - (Pc)][(0 * 64 + lane) * 8];  \
      const bf16x8 ah1 = *(const bf16x8*)&sA2[1 - (Pc)][(1 * 64 + lane) * 8];  \
      f32x4 c2[4];                                                             \
      _Pragma("unroll")                                                        \
      for (int g = 0; g < 4; ++g) {                                            \
        c2[g] = MFMA(ah0, wh2h[g], b2sd[g]);                                   \
        c2[g] = MFMA(ah1, wh2h[g], c2[g]);                                     \
        c2[g] = MFMA(ah0, wh2l[g], c2[g]);                                     \
        c2[g] += *(const f32x4*)&sP[1 - (Pc)][((wl2b * 4 + g) * 64 + lane) * 4]; \
      }                                                                        \
      _Pragma("unroll")                                                        \
      for (int r = 0; r < 4; ++r) {                                            \
        const float iv = fsig(c2[0][r]);                                       \
        const float fv = fsig(c2[1][r]);                                       \
        const float gv = ftanhf(c2[2][r]);                                     \
        const float ov = fsig(c2[3][r]);                                       \
        const float cc = fmaf(fv, c2s[r], iv * gv);                            \
        c2s[r] = cc;                                                           \
        const float hf = ov * ftanhf(cc);                                      \
        __bf16 hh_, hl_;                                                       \
        split_fast(hf, hh_, hl_);                                              \
        const int m = q * 4 + r;                                               \
        sA2[(Pc)][((0 * 64) + lnb2 + m) * 8 + jj2] = hh_;                      \
        sA2[(Pc)][((1 * 64) + lnb2 + m) * 8 + jj2] = hl_;                      \
        if (DO_H2F) sH2f[m * 32 + uu2b] = hf;                                  \
      }                                                                        \
    }                                                                          \
    __syncthreads();                                                           \
  } while (0)

  // -------- pipeline fill --------
  STEP(0, true,  true,  false, false, false, 0);
  STEP(1, true,  true,  true,  false, false, 1);
  // -------- steady state: t = 2..165 (all XPRE: last load at TT=165 -> x(167)) --------
  for (int t = 2; t < 166; t += 2) {
    STEP(0, true, true, true, true, false, t);
    STEP(1, true, true, true, true, false, t + 1);
  }
  // -------- drain --------
  STEP(0, true,  false, true,  true,  false, 166);  // consume x(166); rotate to x(167)
  STEP(1, true,  false, true,  true,  false, 167);  // last L1 step
  STEP(0, false, false, true,  true,  false, 168);  // pA(167), h2(166)
  STEP(1, false, false, false, true,  true,  169);  // h2(167) + final store
#undef STEP

  // ======== FC epilogue ========
  if (tid < NB) {
    float s = bfc[0];
#pragma unroll
    for (int j = 0; j < 32; ++j) s = fmaf(Wfc[j], sH2f[tid * 32 + j], s);
    out[b0 + tid] = s;
  }
}

extern "C" void kernel_launch(void* const* d_in, const int* in_sizes, int n_in,
                              void* d_out, int out_size, void* d_ws, size_t ws_size,
                              hipStream_t stream) {
  (void)in_sizes; (void)n_in; (void)out_size; (void)d_ws; (void)ws_size;
  const float* x    = (const float*)d_in[0];
  const float* Wih1 = (const float*)d_in[1];
  const float* Whh1 = (const float*)d_in[2];
  const float* bih1 = (const float*)d_in[3];
  const float* bhh1 = (const float*)d_in[4];
  const float* Wih2 = (const float*)d_in[5];
  const float* Whh2 = (const float*)d_in[6];
  const float* bih2 = (const float*)d_in[7];
  const float* bhh2 = (const float*)d_in[8];
  const float* Wfc  = (const float*)d_in[9];
  const float* bfc  = (const float*)d_in[10];
  float* out = (float*)d_out;

  hipLaunchKernelGGL(lstm_mfma_kernel, dim3(4096 / NB), dim3(512), 0, stream,
                     x, Wih1, Whh1, bih1, bhh1, Wih2, Whh2, bih2, bhh2, Wfc, bfc, out);
}